// Round 1
// 218.057 us; speedup vs baseline: 1.0000x; 1.0000x over previous
//
#include <hip/hip_runtime.h>

// VoxelModule, round 7.
// lin = (vx*40+vy)*40+vz (< 62359). Coarse bucket c2 = lin>>9 (pow2: shift/mask
// replaces div/mod-11 everywhere). rel = lin&511. Sorting by (c2, rel, idx)
// == sorting by lin == sorting by key (lexicographic in vx,vy,vz), stable via idx.
// pass1: 8 consecutive points/thread via 6 float4 loads; wave0 fused
//        hist-merge + shuffle-scan + gbase; line-dense staging with
//        precomputed gadj/lim (one LDS read less per element).
// pass2: staged tile held in 10 registers (statically unrolled - no scratch),
//        hist + unstable scatter from regs, rank-by-count stability fix.
//        5 barriers, 25 KB LDS (was 9 barriers, 38.6 KB).

#define B 16
#define N 500000
#define BN (B * N)
#define NC2 122          // c2 = lin>>9, lin <= 62358 -> c2 <= 121
#define RELB 512         // rel = lin & 511
#define CAP2 4736        // worst-bucket mean ~4215 (<=500 populated voxels * 8.43), sd ~65 -> +8 sd
#define PPB 4096
#define CPB ((N + PPB - 1) / PPB)   // 123
#define NIT2 ((CAP2 + 511) / 512)   // 10

__global__ __launch_bounds__(512) void pass1(const float* __restrict__ pc,
                                             const int* __restrict__ vs,
                                             int* __restrict__ keys,
                                             int* __restrict__ ccnt,
                                             int* __restrict__ staged) {
    int b = blockIdx.x / CPB;
    int chunk = blockIdx.x % CPB;
    int t = threadIdx.x;
    int w = t >> 6;
    __shared__ int lh[8][NC2];          // per-wave hist -> per-wave exclusive offsets
    __shared__ int lst[NC2];            // block-local exclusive starts
    __shared__ int gadj[NC2];           // c2*CAP2 + gbase - lst  (staged addr = sbase + gadj[c] + p)
    __shared__ int lim[NC2];            // lst + CAP2 - gbase     (guard: p < lim[c])
    __shared__ int buf[PPB];
    __shared__ unsigned char cidb[PPB];
    for (int k = t; k < 8 * NC2; k += 512) ((int*)lh)[k] = 0;
    __syncthreads();
    float scale = (float)(vs[0] - 1);   // 39.0f
    long gb0 = (long)b * N;
    int i0 = chunk * PPB + t * 8;       // 8 consecutive points; N%8==0 -> all-or-nothing
    int c2v[8], rv[8], pk8[8];
    bool valid = (i0 < N);
    if (valid) {
        const float4* F = (const float4*)(pc + 3 * (gb0 + i0));  // 96B-aligned
        float4 f0 = F[0], f1 = F[1], f2 = F[2], f3 = F[3], f4 = F[4], f5 = F[5];
        float xs[8] = {f0.x, f0.w, f1.z, f2.y, f3.x, f3.w, f4.z, f5.y};
        float ys[8] = {f0.y, f1.x, f1.w, f2.z, f3.y, f4.x, f4.w, f5.z};
        float zs[8] = {f0.z, f1.y, f2.x, f2.w, f3.z, f4.y, f5.x, f5.w};
        int kk[8];
#pragma unroll
        for (int j = 0; j < 8; ++j) {
            int vx = (int)(xs[j] * scale);     // trunc == astype(int32)
            int vy = (int)(ys[j] * scale);
            int vz = (int)(zs[j] * scale);
            kk[j] = vx * 10000 + vy * 100 + vz;
            int lin = (vx * 40 + vy) * 40 + vz;
            int c2 = lin >> 9;
            c2v[j] = c2;
            pk8[j] = ((lin & 511) << 19) | (i0 + j);   // 9b rel + 19b idx = 28b
            rv[j] = atomicAdd(&lh[w][c2], 1);
        }
        int4 k0; k0.x = kk[0]; k0.y = kk[1]; k0.z = kk[2]; k0.w = kk[3];
        int4 k1; k1.x = kk[4]; k1.y = kk[5]; k1.z = kk[6]; k1.w = kk[7];
        int4* K = (int4*)(keys + gb0 + i0);
        K[0] = k0; K[1] = k1;
    }
    __syncthreads();
    if (t < 64) {                       // fused: per-wave merge + scan + global base
        int idx0 = 2 * t, idx1 = 2 * t + 1;
        int run0 = 0, run1 = 0;
        if (idx0 < NC2) {
#pragma unroll
            for (int ww = 0; ww < 8; ++ww) { int v = lh[ww][idx0]; lh[ww][idx0] = run0; run0 += v; }
#pragma unroll
            for (int ww = 0; ww < 8; ++ww) { int v = lh[ww][idx1]; lh[ww][idx1] = run1; run1 += v; }
        }
        int s = run0 + run1;
        int x = s;
#pragma unroll
        for (int d = 1; d < 64; d <<= 1) { int y = __shfl_up(x, d, 64); if (t >= d) x += y; }
        int excl = x - s;
        if (idx0 < NC2) {
            int l0 = excl, l1 = excl + run0;
            lst[idx0] = l0; lst[idx1] = l1;
            int g0 = run0 ? atomicAdd(&ccnt[b * NC2 + idx0], run0) : 0;
            int g1 = run1 ? atomicAdd(&ccnt[b * NC2 + idx1], run1) : 0;
            gadj[idx0] = idx0 * CAP2 + g0 - l0;
            gadj[idx1] = idx1 * CAP2 + g1 - l1;
            lim[idx0] = l0 + CAP2 - g0;
            lim[idx1] = l1 + CAP2 - g1;
        }
    }
    __syncthreads();
    if (valid) {                        // block-local split into LDS
#pragma unroll
        for (int j = 0; j < 8; ++j) {
            int c2 = c2v[j];
            int pos = lst[c2] + lh[w][c2] + rv[j];
            buf[pos] = pk8[j];
            cidb[pos] = (unsigned char)c2;
        }
    }
    __syncthreads();
    int nval = N - chunk * PPB; if (nval > PPB) nval = PPB;
    long sbase = (long)b * NC2 * CAP2;
#pragma unroll
    for (int q = 0; q < 8; ++q) {       // line-dense global staging
        int p = t + q * 512;
        if (p < nval) {
            int e = buf[p];
            int c = cidb[p];
            if (p < lim[c]) staged[sbase + gadj[c] + p] = e;
        }
    }
}

__global__ __launch_bounds__(512) void pass2(const int* __restrict__ ccnt,
                                             const int* __restrict__ staged,
                                             int* __restrict__ order_out,
                                             int* __restrict__ skeys_out) {
    int bc = blockIdx.x;
    int b = bc / NC2;
    int c2 = bc % NC2;
    int t = threadIdx.x;
    __shared__ int h[RELB];         // hist, then reused as scatter cursors
    __shared__ int st[RELB + 1];    // bin exclusive starts
    __shared__ int skeyL[RELB];     // rel -> full voxel key
    __shared__ int srt[CAP2];       // unstable-scatter dest
    __shared__ int bsh;             // output base for this bucket
    int cnt = ccnt[bc]; if (cnt > CAP2) cnt = CAP2;
    if (cnt == 0) return;           // uniform: no barriers crossed yet

    // Phase 1: zero hist + skeyL (exactly 1 bin/thread); wave0: output-base scan
    {
        int z = t;                  // RELB == blockDim.x == 512
        h[z] = 0;
        int lin = (c2 << 9) + z;
        int vx = lin / 1600;
        int r = lin - vx * 1600;
        int vy = r / 40;
        int vz = r - vy * 40;
        skeyL[z] = vx * 10000 + vy * 100 + vz;
    }
    if (t < 64) {
        int idx0 = 2 * t, idx1 = 2 * t + 1;
        int v0 = 0, v1 = 0;
        if (idx0 < NC2) {
            v0 = ccnt[b * NC2 + idx0]; if (v0 > CAP2) v0 = CAP2;
            v1 = ccnt[b * NC2 + idx1]; if (v1 > CAP2) v1 = CAP2;
        }
        int s = v0 + v1;
        int x = s;
#pragma unroll
        for (int d = 1; d < 64; d <<= 1) { int y = __shfl_up(x, d, 64); if (t >= d) x += y; }
        int excl = x - s;
        if (idx0 == c2) bsh = excl;
        if (idx1 == c2) bsh = excl + v0;
    }
    __syncthreads();

    // Phase 2: staged tile -> registers + histogram (static unroll: no scratch)
    long rb = (long)bc * CAP2;
    int ev[NIT2];
#pragma unroll
    for (int q = 0; q < NIT2; ++q) {
        int p = t + q * 512;
        if (p < cnt) {
            int e = staged[rb + p];
            ev[q] = e;
            atomicAdd(&h[e >> 19], 1);
        }
    }
    __syncthreads();

    // Phase 3: wave0 scan of 512 bins (8/lane) -> st; reset h as cursors
    if (t < 64) {
        int vals[8]; int s = 0;
#pragma unroll
        for (int j = 0; j < 8; ++j) { int v = h[8 * t + j]; vals[j] = s; s += v; }
        int x = s;
#pragma unroll
        for (int d = 1; d < 64; d <<= 1) { int y = __shfl_up(x, d, 64); if (t >= d) x += y; }
        int excl = x - s;
#pragma unroll
        for (int j = 0; j < 8; ++j) { st[8 * t + j] = excl + vals[j]; h[8 * t + j] = 0; }
        if (t == 63) st[RELB] = x;  // total == cnt
    }
    __syncthreads();

    // Phase 4: unstable LDS scatter from regs
#pragma unroll
    for (int q = 0; q < NIT2; ++q) {
        int p = t + q * 512;
        if (p < cnt) {
            int e = ev[q];
            int z = e >> 19;
            int r = atomicAdd(&h[z], 1);
            srt[st[z] + r] = e;
        }
    }
    __syncthreads();

    // Phase 5: stability via rank-by-count within bin (all values distinct),
    // write final directly to global (dense, lane-permuted within bins).
    long ob = (long)b * N + bsh;
    for (int p = t; p < cnt; p += 512) {
        int v = srt[p];
        int z = v >> 19;
        int s = st[z], e2 = st[z + 1];
        int rank = 0;
        for (int j = s; j < e2; ++j) rank += (srt[j] < v);   // broadcast-heavy reads
        order_out[ob + s + rank] = v & 0x7FFFF;
        skeys_out[ob + s + rank] = skeyL[z];
    }
}

extern "C" void kernel_launch(void* const* d_in, const int* in_sizes, int n_in,
                              void* d_out, int out_size, void* d_ws, size_t ws_size,
                              hipStream_t stream) {
    const float* pc = (const float*)d_in[0];
    const int* vs = (const int*)d_in[1];
    int* out = (int*)d_out;
    int* keys_out = out;            // [B,N]
    int* order_out = out + BN;      // [B,N]
    int* skeys_out = out + 2 * BN;  // [B,N]

    int* ccnt = (int*)d_ws;                 // B*NC2 ints (keeps staged 16B-aligned)
    int* staged = ccnt + B * NC2;           // B*NC2*CAP2 ints = 37.0 MB

    hipMemsetAsync(ccnt, 0, (size_t)B * NC2 * sizeof(int), stream);
    pass1<<<B * CPB, 512, 0, stream>>>(pc, vs, keys_out, ccnt, staged);
    pass2<<<B * NC2, 512, 0, stream>>>(ccnt, staged, order_out, skeys_out);
}